// Round 3
// baseline (13035.973 us; speedup 1.0000x reference)
//
#include <hip/hip_runtime.h>
#include <math.h>

// RNN: L=512, B=128, D=512, H=1024, fp32 in/out.
//   xproj = x @ Wx^T + bx   (65536x1024x512 GEMM) -> written into d_out
//   h_t = tanh(xp_t + h_{t-1} @ Wh^T), in-place over d_out slices.
// Precision: split-bf16 (hi+lo) operands, 3 MFMAs per product => ~fp32 accuracy.
// Round 3: recurrence fused into ONE persistent kernel (256 WGs x 512 thr).
// Batch rows are independent across steps -> 4 independent 64-WG barrier
// groups (one per 32-row mb block) instead of 511 kernel launches.
// Cross-XCD visibility of h via __threadfence (agent wbl2/inv) around a
// relaxed agent-scope arrival counter.

#define L_SEQ 512
#define B_SZ  128
#define D_SZ  512
#define H_SZ  1024
#define BH    (B_SZ * H_SZ)   // 131072

typedef __bf16 bf16x8 __attribute__((ext_vector_type(8)));
typedef float  f32x4  __attribute__((ext_vector_type(4)));

union V8 { bf16x8 b; unsigned short u[8]; };

__device__ __forceinline__ unsigned short f2bf(float f) {
  unsigned int u = __float_as_uint(f);
  u += 0x7FFFu + ((u >> 16) & 1u);   // round-to-nearest-even
  return (unsigned short)(u >> 16);
}
__device__ __forceinline__ float bf2f(unsigned short s) {
  return __uint_as_float(((unsigned int)s) << 16);
}

// ---- d_ws layout (ushort elements unless noted) ----
#define WS_WHH 0            // [1024][1024]
#define WS_WHL 1048576      // [1024][1024]
#define WS_WXH 2097152      // [1024][512]
#define WS_WXL 2621440      // [1024][512]
#define WS_HB  3145728      // [2 parity][2 hi/lo][BH]
#define WS_CNT 3670016      // 4 x uint32 barrier counters (byte off 7340032)

// Split fp32 weights into bf16 hi + bf16 lo(residual); zero barrier counters.
__global__ void split_kernel(const float* __restrict__ Wh,
                             const float* __restrict__ Wx,
                             unsigned short* __restrict__ ws,
                             unsigned int* __restrict__ cnt) {
  if (blockIdx.x == 0 && threadIdx.x < 4) cnt[threadIdx.x] = 0u;
  const int total = 1048576 + 524288;
  for (int i = blockIdx.x * blockDim.x + threadIdx.x; i < total;
       i += gridDim.x * blockDim.x) {
    const float* src; unsigned short *dh, *dl; int j;
    if (i < 1048576) { src = Wh; dh = ws + WS_WHH; dl = ws + WS_WHL; j = i; }
    else             { src = Wx; dh = ws + WS_WXH; dl = ws + WS_WXL; j = i - 1048576; }
    float v = src[j];
    unsigned short h = f2bf(v);
    dh[j] = h;
    dl[j] = f2bf(v - bf2f(h));
  }
}

// xproj: out[m][n] = sum_d x[m][d]*Wx[n][d] + bx[n]  (unchanged from round 2)
__global__ __launch_bounds__(256) void xproj_kernel(
    const float* __restrict__ x,             // [65536][512]
    const unsigned short* __restrict__ wxh,  // [1024][512]
    const unsigned short* __restrict__ wxl,
    const float* __restrict__ bx,            // [1024]
    float* __restrict__ out)                 // [65536][1024]
{
  const int bid = blockIdx.x;
  const int bn = bid & 15;
  const int bm = bid >> 4;
  const int tid = threadIdx.x;
  const int w = tid >> 6, l = tid & 63;
  const int wm = w & 1, wn = w >> 1;
  const int lr = l & 15, lk = (l >> 4) * 8;
  const int mbase = bm * 128 + wm * 64;
  const int nbase = bn * 64 + wn * 32;

  f32x4 acc[4][2] = {};

  for (int k0 = 0; k0 < 512; k0 += 32) {
    bf16x8 ah[4], al[4], bh[2], bl[2];
#pragma unroll
    for (int i = 0; i < 4; ++i) {
      const float* ap = x + (size_t)(mbase + i * 16 + lr) * 512 + k0 + lk;
      float4 v0 = *reinterpret_cast<const float4*>(ap);
      float4 v1 = *reinterpret_cast<const float4*>(ap + 4);
      float vv[8] = {v0.x, v0.y, v0.z, v0.w, v1.x, v1.y, v1.z, v1.w};
      V8 hh, ll;
#pragma unroll
      for (int e = 0; e < 8; ++e) {
        unsigned short hb = f2bf(vv[e]);
        hh.u[e] = hb;
        ll.u[e] = f2bf(vv[e] - bf2f(hb));
      }
      ah[i] = hh.b; al[i] = ll.b;
    }
#pragma unroll
    for (int j = 0; j < 2; ++j) {
      size_t boff = (size_t)(nbase + j * 16 + lr) * 512 + k0 + lk;
      bh[j] = *reinterpret_cast<const bf16x8*>(wxh + boff);
      bl[j] = *reinterpret_cast<const bf16x8*>(wxl + boff);
    }
#pragma unroll
    for (int i = 0; i < 4; ++i)
#pragma unroll
      for (int j = 0; j < 2; ++j) {
        acc[i][j] = __builtin_amdgcn_mfma_f32_16x16x32_bf16(ah[i], bh[j], acc[i][j], 0, 0, 0);
        acc[i][j] = __builtin_amdgcn_mfma_f32_16x16x32_bf16(ah[i], bl[j], acc[i][j], 0, 0, 0);
        acc[i][j] = __builtin_amdgcn_mfma_f32_16x16x32_bf16(al[i], bh[j], acc[i][j], 0, 0, 0);
      }
  }

#pragma unroll
  for (int j = 0; j < 2; ++j) {
    int n = nbase + j * 16 + lr;
    float bxv = bx[n];
#pragma unroll
    for (int i = 0; i < 4; ++i)
#pragma unroll
      for (int r = 0; r < 4; ++r) {
        int m = mbase + i * 16 + (l >> 4) * 4 + r;
        out[(size_t)m * 1024 + n] = acc[i][j][r] + bxv;
      }
  }
}

// Persistent recurrence. 256 WGs x 512 threads; WG (mb,nb) owns the 32x16
// output tile [mb*32..+31] x [nb*16..+15] for ALL 512 steps.
// Wave q (0..7) computes the K-slice [q*128, q*128+128) via split-3-MFMA;
// LDS reduction; epilogue h = tanh(z + xp) written in place to d_out, plus
// bf16 hi/lo state into ping-pong hb buffers.
// Barrier group = mb (4 groups x 64 WGs): batch rows only depend on
// themselves, so only same-mb WGs must sync.
__global__ __launch_bounds__(512) void rnn_persistent(
    const unsigned short* __restrict__ whh,  // [1024][1024]
    const unsigned short* __restrict__ whl,
    unsigned short* __restrict__ hb,         // [2][2][BH]
    float* __restrict__ out,                 // [512][BH] (xproj in, h out)
    unsigned int* __restrict__ cnt)          // [4]
{
  __shared__ float lds[8 * 32 * 17];         // 17408 B, stride-17 pad
  const int wg = blockIdx.x;                 // 0..255
  const int xc = wg & 7, yy = wg >> 3;
  const int mb = xc & 3;                     // barrier group
  const int nb = ((xc >> 2) << 5) + yy;
  const int tid = threadIdx.x;
  const int q = tid >> 6;                    // k-slice 0..7
  const int l = tid & 63;
  const int lr = l & 15, lk = (l >> 4) * 8;
  const int kbase = q * 128 + lk;
  const int row0 = (l >> 4) * 4;

  // B (Wh) pointers — fixed for the whole sequence.
  const unsigned short* bph = whh + (size_t)(nb * 16 + lr) * 1024 + kbase;
  const unsigned short* bpl = whl + (size_t)(nb * 16 + lr) * 1024 + kbase;

  // A (h_prev) base offsets; parity-dependent base added per step.
  const size_t aoff = (size_t)(mb * 32 + lr) * 1024 + kbase;

  // Epilogue mapping: one output element per thread.
  const int em = tid >> 4, en = tid & 15;
  const size_t eidx = (size_t)(mb * 32 + em) * 1024 + nb * 16 + en;

  for (int t = 0; t < L_SEQ; ++t) {
    float* xpt = out + (size_t)t * BH;
    float hval;

    if (t > 0) {
      const unsigned short* hh = hb + (size_t)(((t - 1) & 1) * 2) * BH;
      const unsigned short* hl = hh + BH;
      const unsigned short* a0h = hh + aoff;
      const unsigned short* a0l = hl + aoff;
      const unsigned short* a1h = a0h + 16 * 1024;
      const unsigned short* a1l = a0l + 16 * 1024;

      f32x4 acc0 = {0.f, 0.f, 0.f, 0.f};
      f32x4 acc1 = {0.f, 0.f, 0.f, 0.f};
#pragma unroll
      for (int kb = 0; kb < 4; ++kb) {
        const int ko = kb * 32;
        bf16x8 vA0h = *reinterpret_cast<const bf16x8*>(a0h + ko);
        bf16x8 vA0l = *reinterpret_cast<const bf16x8*>(a0l + ko);
        bf16x8 vA1h = *reinterpret_cast<const bf16x8*>(a1h + ko);
        bf16x8 vA1l = *reinterpret_cast<const bf16x8*>(a1l + ko);
        bf16x8 vBh  = *reinterpret_cast<const bf16x8*>(bph + ko);
        bf16x8 vBl  = *reinterpret_cast<const bf16x8*>(bpl + ko);
        acc0 = __builtin_amdgcn_mfma_f32_16x16x32_bf16(vA0h, vBh, acc0, 0, 0, 0);
        acc1 = __builtin_amdgcn_mfma_f32_16x16x32_bf16(vA1h, vBh, acc1, 0, 0, 0);
        acc0 = __builtin_amdgcn_mfma_f32_16x16x32_bf16(vA0h, vBl, acc0, 0, 0, 0);
        acc1 = __builtin_amdgcn_mfma_f32_16x16x32_bf16(vA1h, vBl, acc1, 0, 0, 0);
        acc0 = __builtin_amdgcn_mfma_f32_16x16x32_bf16(vA0l, vBh, acc0, 0, 0, 0);
        acc1 = __builtin_amdgcn_mfma_f32_16x16x32_bf16(vA1l, vBh, acc1, 0, 0, 0);
      }

      // Partials -> LDS. C/D layout: col = lane&15, row = (lane>>4)*4 + r.
#pragma unroll
      for (int r = 0; r < 4; ++r) {
        lds[q * 544 + (row0 + r) * 17 + lr]      = acc0[r];
        lds[q * 544 + (16 + row0 + r) * 17 + lr] = acc1[r];
      }
      __syncthreads();

      float s = 0.f;
#pragma unroll
      for (int qq = 0; qq < 8; ++qq) s += lds[qq * 544 + em * 17 + en];
      hval = tanhf(s + xpt[eidx]);
    } else {
      hval = tanhf(xpt[eidx]);
    }

    // Write outputs: fp32 h in place; bf16 hi/lo state into parity t&1.
    xpt[eidx] = hval;
    unsigned short hhi = f2bf(hval);
    unsigned short* hcur = hb + (size_t)((t & 1) * 2) * BH;
    hcur[eidx] = hhi;
    (hcur + BH)[eidx] = f2bf(hval - bf2f(hhi));

    // Group barrier: all 64 WGs with this mb must finish step t.
    __syncthreads();   // drains vmcnt for all waves -> stores are in L2
    if (tid == 0) {
      __threadfence(); // agent release: writeback L2 to coherence point
      __hip_atomic_fetch_add(cnt + mb, 1u, __ATOMIC_RELAXED,
                             __HIP_MEMORY_SCOPE_AGENT);
      const unsigned int tgt = 64u * (unsigned int)(t + 1);
      while (__hip_atomic_load(cnt + mb, __ATOMIC_RELAXED,
                               __HIP_MEMORY_SCOPE_AGENT) < tgt) {
        __builtin_amdgcn_s_sleep(2);
      }
      __threadfence(); // agent acquire: invalidate L2 -> fresh h reads
    }
    __syncthreads();
  }
}

extern "C" void kernel_launch(void* const* d_in, const int* in_sizes, int n_in,
                              void* d_out, int out_size, void* d_ws, size_t ws_size,
                              hipStream_t stream) {
  const float* x  = (const float*)d_in[0];   // [512][128][512]
  const float* Wx = (const float*)d_in[1];   // [1024][512]
  const float* bx = (const float*)d_in[2];   // [1024]
  const float* Wh = (const float*)d_in[3];   // [1024][1024]
  float* out = (float*)d_out;                // [512][128][1024]
  unsigned short* ws = (unsigned short*)d_ws;

  unsigned short* whh = ws + WS_WHH;
  unsigned short* whl = ws + WS_WHL;
  unsigned short* wxh = ws + WS_WXH;
  unsigned short* wxl = ws + WS_WXL;
  unsigned short* hb  = ws + WS_HB;          // [2][2][BH]
  unsigned int*   cnt = (unsigned int*)(ws + WS_CNT);

  split_kernel<<<dim3(2048), dim3(256), 0, stream>>>(Wh, Wx, ws, cnt);
  xproj_kernel<<<dim3(8192), dim3(256), 0, stream>>>(x, wxh, wxl, bx, out);
  rnn_persistent<<<dim3(256), dim3(512), 0, stream>>>(whh, whl, hb, out, cnt);
}

// Round 4
// 6623.135 us; speedup vs baseline: 1.9682x; 1.9682x over previous
//
#include <hip/hip_runtime.h>
#include <math.h>

// RNN: L=512, B=128, D=512, H=1024, fp32 in/out.
//   xproj = x @ Wx^T + bx   (65536x1024x512 GEMM) -> written into d_out
//   h_t = tanh(xp_t + h_{t-1} @ Wh^T), in-place over d_out slices.
// Precision: split-bf16 (hi+lo) operands, 3 MFMAs per product => ~fp32 accuracy.
// Round 4: persistent kernel kept, but __threadfence (buffer_wbl2/buffer_inv —
// it was invalidating the whole L2 incl. Wh every step, 97% idle) replaced by
// FENCE-FREE protocol: h-state exchanged via agent-scope relaxed atomics
// (sc0 sc1: write-through to L3 / L1+L2-bypass loads). Wh stays L2-resident.
// Ordering: sc1 stores ack from coherence point, drained by the vmcnt(0) in
// __syncthreads before tid0's relaxed arrival fetch_add.

#define L_SEQ 512
#define B_SZ  128
#define D_SZ  512
#define H_SZ  1024
#define BH    (B_SZ * H_SZ)   // 131072

typedef __bf16 bf16x8 __attribute__((ext_vector_type(8)));
typedef float  f32x4  __attribute__((ext_vector_type(4)));

union V8 { bf16x8 b; unsigned short u[8]; };

__device__ __forceinline__ unsigned short f2bf(float f) {
  unsigned int u = __float_as_uint(f);
  u += 0x7FFFu + ((u >> 16) & 1u);   // round-to-nearest-even
  return (unsigned short)(u >> 16);
}
__device__ __forceinline__ float bf2f(unsigned short s) {
  return __uint_as_float(((unsigned int)s) << 16);
}

// 16B fragment as two 8B agent-scope relaxed loads (sc0 sc1: bypass L1/L2,
// read the L3 coherence point -> always-fresh h state, no cache fences).
__device__ __forceinline__ bf16x8 ld_hb16(const unsigned short* p) {
  union { bf16x8 v; unsigned long long q[2]; } u;
  u.q[0] = __hip_atomic_load((const unsigned long long*)p,
                             __ATOMIC_RELAXED, __HIP_MEMORY_SCOPE_AGENT);
  u.q[1] = __hip_atomic_load((const unsigned long long*)(p + 4),
                             __ATOMIC_RELAXED, __HIP_MEMORY_SCOPE_AGENT);
  return u.v;
}

// ---- d_ws layout (ushort elements unless noted) ----
#define WS_WHH 0            // [1024][1024]
#define WS_WHL 1048576      // [1024][1024]
#define WS_WXH 2097152      // [1024][512]
#define WS_WXL 2621440      // [1024][512]
#define WS_HB  3145728      // [2 parity][2 hi/lo][BH]
#define WS_CNT 3670016      // 4 x uint32 barrier counters

// Split fp32 weights into bf16 hi + bf16 lo(residual); zero barrier counters.
__global__ void split_kernel(const float* __restrict__ Wh,
                             const float* __restrict__ Wx,
                             unsigned short* __restrict__ ws,
                             unsigned int* __restrict__ cnt) {
  if (blockIdx.x == 0 && threadIdx.x < 4) cnt[threadIdx.x] = 0u;
  const int total = 1048576 + 524288;
  for (int i = blockIdx.x * blockDim.x + threadIdx.x; i < total;
       i += gridDim.x * blockDim.x) {
    const float* src; unsigned short *dh, *dl; int j;
    if (i < 1048576) { src = Wh; dh = ws + WS_WHH; dl = ws + WS_WHL; j = i; }
    else             { src = Wx; dh = ws + WS_WXH; dl = ws + WS_WXL; j = i - 1048576; }
    float v = src[j];
    unsigned short h = f2bf(v);
    dh[j] = h;
    dl[j] = f2bf(v - bf2f(h));
  }
}

// xproj: out[m][n] = sum_d x[m][d]*Wx[n][d] + bx[n]  (unchanged)
__global__ __launch_bounds__(256) void xproj_kernel(
    const float* __restrict__ x,             // [65536][512]
    const unsigned short* __restrict__ wxh,  // [1024][512]
    const unsigned short* __restrict__ wxl,
    const float* __restrict__ bx,            // [1024]
    float* __restrict__ out)                 // [65536][1024]
{
  const int bid = blockIdx.x;
  const int bn = bid & 15;
  const int bm = bid >> 4;
  const int tid = threadIdx.x;
  const int w = tid >> 6, l = tid & 63;
  const int wm = w & 1, wn = w >> 1;
  const int lr = l & 15, lk = (l >> 4) * 8;
  const int mbase = bm * 128 + wm * 64;
  const int nbase = bn * 64 + wn * 32;

  f32x4 acc[4][2] = {};

  for (int k0 = 0; k0 < 512; k0 += 32) {
    bf16x8 ah[4], al[4], bh[2], bl[2];
#pragma unroll
    for (int i = 0; i < 4; ++i) {
      const float* ap = x + (size_t)(mbase + i * 16 + lr) * 512 + k0 + lk;
      float4 v0 = *reinterpret_cast<const float4*>(ap);
      float4 v1 = *reinterpret_cast<const float4*>(ap + 4);
      float vv[8] = {v0.x, v0.y, v0.z, v0.w, v1.x, v1.y, v1.z, v1.w};
      V8 hh, ll;
#pragma unroll
      for (int e = 0; e < 8; ++e) {
        unsigned short hb = f2bf(vv[e]);
        hh.u[e] = hb;
        ll.u[e] = f2bf(vv[e] - bf2f(hb));
      }
      ah[i] = hh.b; al[i] = ll.b;
    }
#pragma unroll
    for (int j = 0; j < 2; ++j) {
      size_t boff = (size_t)(nbase + j * 16 + lr) * 512 + k0 + lk;
      bh[j] = *reinterpret_cast<const bf16x8*>(wxh + boff);
      bl[j] = *reinterpret_cast<const bf16x8*>(wxl + boff);
    }
#pragma unroll
    for (int i = 0; i < 4; ++i)
#pragma unroll
      for (int j = 0; j < 2; ++j) {
        acc[i][j] = __builtin_amdgcn_mfma_f32_16x16x32_bf16(ah[i], bh[j], acc[i][j], 0, 0, 0);
        acc[i][j] = __builtin_amdgcn_mfma_f32_16x16x32_bf16(ah[i], bl[j], acc[i][j], 0, 0, 0);
        acc[i][j] = __builtin_amdgcn_mfma_f32_16x16x32_bf16(al[i], bh[j], acc[i][j], 0, 0, 0);
      }
  }

#pragma unroll
  for (int j = 0; j < 2; ++j) {
    int n = nbase + j * 16 + lr;
    float bxv = bx[n];
#pragma unroll
    for (int i = 0; i < 4; ++i)
#pragma unroll
      for (int r = 0; r < 4; ++r) {
        int m = mbase + i * 16 + (l >> 4) * 4 + r;
        out[(size_t)m * 1024 + n] = acc[i][j][r] + bxv;
      }
  }
}

// Persistent recurrence (fence-free). 256 WGs x 512 threads; WG (mb,nb) owns
// the 32x16 output tile for ALL steps. Wave q: K-slice [q*128,+128).
// Barrier group = mb (4 groups x 64 WGs; batch rows independent across steps).
__global__ __launch_bounds__(512) void rnn_persistent(
    const unsigned short* __restrict__ whh,  // [1024][1024]
    const unsigned short* __restrict__ whl,
    unsigned short* __restrict__ hb,         // [2][2][BH]
    float* __restrict__ out,                 // [512][BH] (xproj in, h out)
    unsigned int* __restrict__ cnt)          // [4]
{
  __shared__ float lds[8 * 32 * 17];         // 17408 B, stride-17 pad
  const int wg = blockIdx.x;                 // 0..255
  const int xc = wg & 7, yy = wg >> 3;
  const int mb = xc & 3;                     // barrier group
  const int nb = ((xc >> 2) << 5) + yy;
  const int tid = threadIdx.x;
  const int q = tid >> 6;                    // k-slice 0..7
  const int l = tid & 63;
  const int lr = l & 15, lk = (l >> 4) * 8;
  const int kbase = q * 128 + lk;
  const int row0 = (l >> 4) * 4;

  // B (Wh) pointers — fixed, ordinary cached loads (L2-resident forever).
  const unsigned short* bph = whh + (size_t)(nb * 16 + lr) * 1024 + kbase;
  const unsigned short* bpl = whl + (size_t)(nb * 16 + lr) * 1024 + kbase;

  // A (h_prev) offset within a parity plane.
  const size_t aoff = (size_t)(mb * 32 + lr) * 1024 + kbase;

  // Epilogue mapping: one output element per thread.
  const int em = tid >> 4, en = tid & 15;
  const size_t eidx = (size_t)(mb * 32 + em) * 1024 + nb * 16 + en;

  for (int t = 0; t < L_SEQ; ++t) {
    float* xpt = out + (size_t)t * BH;
    float hval;

    if (t > 0) {
      const unsigned short* hh = hb + (size_t)(((t - 1) & 1) * 2) * BH;
      const unsigned short* hl = hh + BH;
      const unsigned short* a0h = hh + aoff;
      const unsigned short* a0l = hl + aoff;
      const unsigned short* a1h = a0h + 16 * 1024;
      const unsigned short* a1l = a0l + 16 * 1024;

      f32x4 acc0 = {0.f, 0.f, 0.f, 0.f};
      f32x4 acc1 = {0.f, 0.f, 0.f, 0.f};
#pragma unroll
      for (int kb = 0; kb < 4; ++kb) {
        const int ko = kb * 32;
        bf16x8 vA0h = ld_hb16(a0h + ko);
        bf16x8 vA0l = ld_hb16(a0l + ko);
        bf16x8 vA1h = ld_hb16(a1h + ko);
        bf16x8 vA1l = ld_hb16(a1l + ko);
        bf16x8 vBh  = *reinterpret_cast<const bf16x8*>(bph + ko);
        bf16x8 vBl  = *reinterpret_cast<const bf16x8*>(bpl + ko);
        acc0 = __builtin_amdgcn_mfma_f32_16x16x32_bf16(vA0h, vBh, acc0, 0, 0, 0);
        acc1 = __builtin_amdgcn_mfma_f32_16x16x32_bf16(vA1h, vBh, acc1, 0, 0, 0);
        acc0 = __builtin_amdgcn_mfma_f32_16x16x32_bf16(vA0h, vBl, acc0, 0, 0, 0);
        acc1 = __builtin_amdgcn_mfma_f32_16x16x32_bf16(vA1h, vBl, acc1, 0, 0, 0);
        acc0 = __builtin_amdgcn_mfma_f32_16x16x32_bf16(vA0l, vBh, acc0, 0, 0, 0);
        acc1 = __builtin_amdgcn_mfma_f32_16x16x32_bf16(vA1l, vBh, acc1, 0, 0, 0);
      }

      // Partials -> LDS. C/D layout: col = lane&15, row = (lane>>4)*4 + r.
#pragma unroll
      for (int r = 0; r < 4; ++r) {
        lds[q * 544 + (row0 + r) * 17 + lr]      = acc0[r];
        lds[q * 544 + (16 + row0 + r) * 17 + lr] = acc1[r];
      }
      __syncthreads();

      float s = 0.f;
#pragma unroll
      for (int qq = 0; qq < 8; ++qq) s += lds[qq * 544 + em * 17 + en];
      hval = tanhf(s + xpt[eidx]);
      __syncthreads();   // lds reads done before next-step overwrite
    } else {
      hval = tanhf(xpt[eidx]);
    }

    // fp32 h in place (thread-private, ordinary cached store).
    xpt[eidx] = hval;
    // bf16 hi/lo state: agent-scope relaxed atomic stores (sc0 sc1 ->
    // write-through to the L3 coherence point; no cache fences needed).
    unsigned short hhi = f2bf(hval);
    unsigned short hlo = f2bf(hval - bf2f(hhi));
    unsigned short* hcur = hb + (size_t)((t & 1) * 2) * BH;
    __hip_atomic_store(hcur + eidx, hhi, __ATOMIC_RELAXED,
                       __HIP_MEMORY_SCOPE_AGENT);
    __hip_atomic_store(hcur + BH + eidx, hlo, __ATOMIC_RELAXED,
                       __HIP_MEMORY_SCOPE_AGENT);

    // Group barrier. __syncthreads drains vmcnt(0): sc1 stores ack from the
    // coherence point, so after it all h-state is L3-visible -> relaxed add.
    __syncthreads();
    if (tid == 0) {
      __hip_atomic_fetch_add(cnt + mb, 1u, __ATOMIC_RELAXED,
                             __HIP_MEMORY_SCOPE_AGENT);
      const unsigned int tgt = 64u * (unsigned int)(t + 1);
      while (__hip_atomic_load(cnt + mb, __ATOMIC_RELAXED,
                               __HIP_MEMORY_SCOPE_AGENT) < tgt) {
        __builtin_amdgcn_s_sleep(1);
      }
    }
    __syncthreads();
    // Readers fetch h via sc1 loads (L1/L2 bypass) -> no acquire fence.
  }
}

extern "C" void kernel_launch(void* const* d_in, const int* in_sizes, int n_in,
                              void* d_out, int out_size, void* d_ws, size_t ws_size,
                              hipStream_t stream) {
  const float* x  = (const float*)d_in[0];   // [512][128][512]
  const float* Wx = (const float*)d_in[1];   // [1024][512]
  const float* bx = (const float*)d_in[2];   // [1024]
  const float* Wh = (const float*)d_in[3];   // [1024][1024]
  float* out = (float*)d_out;                // [512][128][1024]
  unsigned short* ws = (unsigned short*)d_ws;

  unsigned short* whh = ws + WS_WHH;
  unsigned short* whl = ws + WS_WHL;
  unsigned short* wxh = ws + WS_WXH;
  unsigned short* wxl = ws + WS_WXL;
  unsigned short* hb  = ws + WS_HB;          // [2][2][BH]
  unsigned int*   cnt = (unsigned int*)(ws + WS_CNT);

  split_kernel<<<dim3(2048), dim3(256), 0, stream>>>(Wh, Wx, ws, cnt);
  xproj_kernel<<<dim3(8192), dim3(256), 0, stream>>>(x, wxh, wxl, bx, out);
  rnn_persistent<<<dim3(256), dim3(512), 0, stream>>>(whh, whl, hb, out, cnt);
}